// Round 3
// baseline (70.436 us; speedup 1.0000x reference)
//
#include <hip/hip_runtime.h>

#define NT 256

__device__ __forceinline__ int refl(int i, int n) {
    i = (i < 0) ? (-i - 1) : i;
    i = (i >= n) ? (2 * n - 1 - i) : i;
    return i;
}

// One fused 2D DWT level, 32x32 output tile per block.
// out[i] = sum_k f[k] * x[refl(2i+1-k)]  (both axes).
// Phase A: global -> horizontal lo/hi conv -> LDS s[t][2c]=lo, s[t][2c+1]=hi
//   (t = halo row 0..69 <-> input row rb+t, pitch 66 -> conflict-free)
// Phase B: vertical conv from LDS -> 4 subbands.
__global__ __launch_bounds__(256, 8)
void dwt2_fused(const float* __restrict__ in, int n, int ldin, int inb,
                int m,
                float* __restrict__ oA, int ldA, int Ab,
                float* __restrict__ oH, float* __restrict__ oV, float* __restrict__ oD)
{
    constexpr float LOF[8] = {
        -0.010597401784997278f,  0.032883011666982945f,
         0.030841381835986965f, -0.18703481171888114f,
        -0.02798376941698385f,   0.6308807679295904f,
         0.7148465705525415f,    0.23037781330885523f };
    constexpr float HIF[8] = {
        -0.23037781330885523f,   0.7148465705525415f,
        -0.6308807679295904f,   -0.02798376941698385f,
         0.18703481171888114f,   0.030841381835986965f,
        -0.032883011666982945f, -0.010597401784997278f };

    __shared__ float s[70][66];   // 18480 B

    const int tid = threadIdx.x;
    const int c0 = blockIdx.x * 32, r0 = blockIdx.y * 32;
    const int b  = blockIdx.z;
    const float* Ain = in + b * inb;          // all offsets < 2^24, int math

    const int rb = 2 * r0 - 6;                // LDS row t <-> input row rb+t
    const int cb = 2 * c0 - 8;                // qc window base: cols cb+8qc .. +15

    const bool interior = (rb >= 0) && (rb + 69 < n) && (cb >= 0) && (cb + 71 < n);

    // ---- Phase A: 70 halo rows x 8 quad-cols (4 output cols each) ----
    if (interior) {
        for (int idx = tid; idx < 560; idx += NT) {
            const int tr = idx >> 3, qc = idx & 7;
            const float* p = Ain + (rb + tr) * ldin + (cb + 8 * qc);
            const float4 a0 = *(const float4*)(p);
            const float4 a1 = *(const float4*)(p + 4);
            const float4 a2 = *(const float4*)(p + 8);
            const float4 a3 = *(const float4*)(p + 12);
            const float v[16] = { a0.x, a0.y, a0.z, a0.w,
                                  a1.x, a1.y, a1.z, a1.w,
                                  a2.x, a2.y, a2.z, a2.w,
                                  a3.x, a3.y, a3.z, a3.w };
            float* srow = &s[tr][8 * qc];
            #pragma unroll
            for (int d = 0; d < 4; ++d) {
                float lo = 0.f, hi = 0.f;
                #pragma unroll
                for (int k = 0; k < 8; ++k) {
                    const float x = v[2 * d + 9 - k];
                    lo += LOF[k] * x;
                    hi += HIF[k] * x;
                }
                *(float2*)(srow + 2 * d) = make_float2(lo, hi);
            }
        }
    } else {
        for (int idx = tid; idx < 560; idx += NT) {
            const int tr = idx >> 3, qc = idx & 7;
            const float* row = Ain + refl(rb + tr, n) * ldin;
            const int cw = cb + 8 * qc;
            float v[16];
            v[0] = 0.f; v[1] = 0.f;
            #pragma unroll
            for (int u = 2; u < 16; ++u) v[u] = row[refl(cw + u, n)];
            float* srow = &s[tr][8 * qc];
            #pragma unroll
            for (int d = 0; d < 4; ++d) {
                float lo = 0.f, hi = 0.f;
                #pragma unroll
                for (int k = 0; k < 8; ++k) {
                    const float x = v[2 * d + 9 - k];
                    lo += LOF[k] * x;
                    hi += HIF[k] * x;
                }
                *(float2*)(srow + 2 * d) = make_float2(lo, hi);
            }
        }
    }
    __syncthreads();

    // ---- Phase B: 32 cols x 16 row-pairs ----
    const int ob = b * (m * m);
    const int oa = b * Ab;
    for (int idx = tid; idx < 512; idx += NT) {
        const int c = idx & 31, pr = idx >> 5;
        float lo[10], hi[10];
        #pragma unroll
        for (int j = 0; j < 10; ++j) {
            const float2 w = *(const float2*)&s[4 * pr + j][2 * c];
            lo[j] = w.x; hi[j] = w.y;
        }
        float A0 = 0.f, H0 = 0.f, V0 = 0.f, D0 = 0.f;
        float A1 = 0.f, H1 = 0.f, V1 = 0.f, D1 = 0.f;
        #pragma unroll
        for (int k = 0; k < 8; ++k) {
            const float l0 = lo[7 - k], h0 = hi[7 - k];
            const float l1 = lo[9 - k], h1 = hi[9 - k];
            A0 += LOF[k] * l0;  H0 += HIF[k] * l0;
            V0 += LOF[k] * h0;  D0 += HIF[k] * h0;
            A1 += LOF[k] * l1;  H1 += HIF[k] * l1;
            V1 += LOF[k] * h1;  D1 += HIF[k] * h1;
        }
        const int gr = r0 + 2 * pr, gc = c0 + c;
        if (gc < m) {
            const int od = gr * m + gc;
            if (gr < m) {
                oA[oa + gr * ldA + gc] = A0;
                __builtin_nontemporal_store(H0, &oH[ob + od]);
                __builtin_nontemporal_store(V0, &oV[ob + od]);
                __builtin_nontemporal_store(D0, &oD[ob + od]);
            }
            if (gr + 1 < m) {
                oA[oa + (gr + 1) * ldA + gc] = A1;
                __builtin_nontemporal_store(H1, &oH[ob + od + m]);
                __builtin_nontemporal_store(V1, &oV[ob + od + m]);
                __builtin_nontemporal_store(D1, &oD[ob + od + m]);
            }
        }
    }
}

extern "C" void kernel_launch(void* const* d_in, const int* in_sizes, int n_in,
                              void* d_out, int out_size, void* d_ws, size_t ws_size,
                              hipStream_t stream) {
    const float* x = (const float*)d_in[0];
    float* out = (float*)d_out;
    float* ws  = (float*)d_ws;

    const int B = 16;
    const int n1 = 1024, m1 = 515;
    const int n2 = 515,  m2 = 261;
    const int n3 = 261,  m3 = 134;

    // padded cA intermediates (16B-aligned rows)
    const int ld1 = 516, b1 = m1 * ld1;   // 265,740
    const int ld2 = 264, b2 = m2 * ld2;   //  68,904
    float* a1 = ws;
    float* a2 = ws + (size_t)b1 * B;

    const size_t sz1 = (size_t)B * m1 * m1;
    const size_t sz2 = (size_t)B * m2 * m2;
    const size_t sz3 = (size_t)B * m3 * m3;

    // d_out: a3, lh3, hl3, hh3, lh2, hl2, hh2, lh1, hl1, hh1
    float* a3  = out;
    float* lh3 = a3  + sz3;
    float* hl3 = lh3 + sz3;
    float* hh3 = hl3 + sz3;
    float* lh2 = hh3 + sz3;
    float* hl2 = lh2 + sz2;
    float* hh2 = hl2 + sz2;
    float* lh1 = hh2 + sz2;
    float* hl1 = lh1 + sz1;
    float* hh1 = hl1 + sz1;

    dim3 blk(NT);
    dim3 g1((m1 + 31) / 32, (m1 + 31) / 32, B);
    dim3 g2((m2 + 31) / 32, (m2 + 31) / 32, B);
    dim3 g3((m3 + 31) / 32, (m3 + 31) / 32, B);

    dwt2_fused<<<g1, blk, 0, stream>>>(x,  n1, n1, n1 * n1,
                                       m1, a1, ld1, b1, lh1, hl1, hh1);
    dwt2_fused<<<g2, blk, 0, stream>>>(a1, n2, ld1, b1,
                                       m2, a2, ld2, b2, lh2, hl2, hh2);
    dwt2_fused<<<g3, blk, 0, stream>>>(a2, n3, ld2, b2,
                                       m3, out, m3, m3 * m3, lh3, hl3, hh3);
}

// Round 5
// 58.869 us; speedup vs baseline: 1.1965x; 1.1965x over previous
//
#include <hip/hip_runtime.h>

#define NT 256

__device__ __forceinline__ int refl(int i, int n) {
    i = (i < 0) ? (-i - 1) : i;
    i = (i >= n) ? (2 * n - 1 - i) : i;
    return i;
}

// One fused 2D DWT level, 32x32 output tile per block.
// out[i] = sum_k f[k] * x[refl(2i+1-k)]  (both axes).
// 1-D grid, bijective XCD-chunked swizzle (nwg = gridDim.x!), tiles ordered
// y-fastest so vertically-adjacent tiles (sharing 38 halo rows) stay on one XCD.
// Phase A: global -> horizontal lo/hi conv -> LDS s[t][2c]=lo, s[t][2c+1]=hi
// Phase B: vertical conv from LDS -> 4 subbands.
__global__ __launch_bounds__(256, 8)
void dwt2_fused(const float* __restrict__ in, int n, int ldin, int inb,
                int m, int nty, int ntx,
                float* __restrict__ oA, int ldA, int Ab,
                float* __restrict__ oH, float* __restrict__ oV, float* __restrict__ oD)
{
    constexpr float LOF[8] = {
        -0.010597401784997278f,  0.032883011666982945f,
         0.030841381835986965f, -0.18703481171888114f,
        -0.02798376941698385f,   0.6308807679295904f,
         0.7148465705525415f,    0.23037781330885523f };
    constexpr float HIF[8] = {
        -0.23037781330885523f,   0.7148465705525415f,
        -0.6308807679295904f,   -0.02798376941698385f,
         0.18703481171888114f,   0.030841381835986965f,
        -0.032883011666982945f, -0.010597401784997278f };

    __shared__ float s[70][66];   // 18480 B

    // --- bijective XCD-chunked remap (m204), y-fastest tile order ---
    const int nwg  = gridDim.x;                // total workgroups (ntx*nty*B)
    const int wgid = blockIdx.x;
    const int q = nwg >> 3, r = nwg & 7;
    const int xcd = wgid & 7, pos = wgid >> 3;
    const int start = xcd * q + (xcd < r ? xcd : r);
    const int i = start + pos;                 // contiguous run per XCD
    const int ty = i % nty;
    const int t2 = i / nty;
    const int tx = t2 % ntx;
    const int b  = t2 / ntx;

    const int tid = threadIdx.x;
    const int c0 = tx * 32, r0 = ty * 32;
    const float* Ain = in + b * inb;

    const int rb = 2 * r0 - 6;                // LDS row t <-> input row rb+t
    const int cb = 2 * c0 - 8;                // qc window base: cols cb+8qc .. +15

    const bool interior = (rb >= 0) && (rb + 69 < n) && (cb >= 0) && (cb + 71 < n);

    // ---- Phase A: 70 halo rows x 8 quad-cols (4 output cols each) ----
    if (interior) {
        for (int idx = tid; idx < 560; idx += NT) {
            const int tr = idx >> 3, qc = idx & 7;
            const float* p = Ain + (rb + tr) * ldin + (cb + 8 * qc);
            const float4 a0 = *(const float4*)(p);
            const float4 a1 = *(const float4*)(p + 4);
            const float4 a2 = *(const float4*)(p + 8);
            const float4 a3 = *(const float4*)(p + 12);
            const float v[16] = { a0.x, a0.y, a0.z, a0.w,
                                  a1.x, a1.y, a1.z, a1.w,
                                  a2.x, a2.y, a2.z, a2.w,
                                  a3.x, a3.y, a3.z, a3.w };
            float* srow = &s[tr][8 * qc];
            #pragma unroll
            for (int d = 0; d < 4; ++d) {
                float lo = 0.f, hi = 0.f;
                #pragma unroll
                for (int k = 0; k < 8; ++k) {
                    const float x = v[2 * d + 9 - k];
                    lo += LOF[k] * x;
                    hi += HIF[k] * x;
                }
                *(float2*)(srow + 2 * d) = make_float2(lo, hi);
            }
        }
    } else {
        for (int idx = tid; idx < 560; idx += NT) {
            const int tr = idx >> 3, qc = idx & 7;
            const float* row = Ain + refl(rb + tr, n) * ldin;
            const int cw = cb + 8 * qc;
            float v[16];
            v[0] = 0.f; v[1] = 0.f;
            #pragma unroll
            for (int u = 2; u < 16; ++u) v[u] = row[refl(cw + u, n)];
            float* srow = &s[tr][8 * qc];
            #pragma unroll
            for (int d = 0; d < 4; ++d) {
                float lo = 0.f, hi = 0.f;
                #pragma unroll
                for (int k = 0; k < 8; ++k) {
                    const float x = v[2 * d + 9 - k];
                    lo += LOF[k] * x;
                    hi += HIF[k] * x;
                }
                *(float2*)(srow + 2 * d) = make_float2(lo, hi);
            }
        }
    }
    __syncthreads();

    // ---- Phase B: 32 cols x 16 row-pairs ----
    const int ob = b * (m * m);
    const int oa = b * Ab;
    for (int idx = tid; idx < 512; idx += NT) {
        const int c = idx & 31, pr = idx >> 5;
        float lo[10], hi[10];
        #pragma unroll
        for (int j = 0; j < 10; ++j) {
            const float2 w = *(const float2*)&s[4 * pr + j][2 * c];
            lo[j] = w.x; hi[j] = w.y;
        }
        float A0 = 0.f, H0 = 0.f, V0 = 0.f, D0 = 0.f;
        float A1 = 0.f, H1 = 0.f, V1 = 0.f, D1 = 0.f;
        #pragma unroll
        for (int k = 0; k < 8; ++k) {
            const float l0 = lo[7 - k], h0 = hi[7 - k];
            const float l1 = lo[9 - k], h1 = hi[9 - k];
            A0 += LOF[k] * l0;  H0 += HIF[k] * l0;
            V0 += LOF[k] * h0;  D0 += HIF[k] * h0;
            A1 += LOF[k] * l1;  H1 += HIF[k] * l1;
            V1 += LOF[k] * h1;  D1 += HIF[k] * h1;
        }
        const int gr = r0 + 2 * pr, gc = c0 + c;
        if (gc < m) {
            const int od = gr * m + gc;
            if (gr < m) {
                oA[oa + gr * ldA + gc] = A0;
                oH[ob + od] = H0; oV[ob + od] = V0; oD[ob + od] = D0;
            }
            if (gr + 1 < m) {
                oA[oa + (gr + 1) * ldA + gc] = A1;
                oH[ob + od + m] = H1; oV[ob + od + m] = V1; oD[ob + od + m] = D1;
            }
        }
    }
}

extern "C" void kernel_launch(void* const* d_in, const int* in_sizes, int n_in,
                              void* d_out, int out_size, void* d_ws, size_t ws_size,
                              hipStream_t stream) {
    const float* x = (const float*)d_in[0];
    float* out = (float*)d_out;
    float* ws  = (float*)d_ws;

    const int B = 16;
    const int n1 = 1024, m1 = 515;
    const int n2 = 515,  m2 = 261;
    const int n3 = 261,  m3 = 134;

    // padded cA intermediates (16B-aligned rows)
    const int ld1 = 516, b1 = m1 * ld1;
    const int ld2 = 264, b2 = m2 * ld2;
    float* a1 = ws;
    float* a2 = ws + (size_t)b1 * B;

    const size_t sz1 = (size_t)B * m1 * m1;
    const size_t sz2 = (size_t)B * m2 * m2;
    const size_t sz3 = (size_t)B * m3 * m3;

    // d_out: a3, lh3, hl3, hh3, lh2, hl2, hh2, lh1, hl1, hh1
    float* a3  = out;
    float* lh3 = a3  + sz3;
    float* hl3 = lh3 + sz3;
    float* hh3 = hl3 + sz3;
    float* lh2 = hh3 + sz3;
    float* hl2 = lh2 + sz2;
    float* hh2 = hl2 + sz2;
    float* lh1 = hh2 + sz2;
    float* hl1 = lh1 + sz1;
    float* hh1 = hl1 + sz1;

    const int t1 = (m1 + 31) / 32;   // 17
    const int t2_ = (m2 + 31) / 32;  // 9
    const int t3 = (m3 + 31) / 32;   // 5

    dim3 blk(NT);
    dim3 g1(t1 * t1 * B, 1, 1);
    dim3 g2(t2_ * t2_ * B, 1, 1);
    dim3 g3(t3 * t3 * B, 1, 1);

    dwt2_fused<<<g1, blk, 0, stream>>>(x,  n1, n1, n1 * n1,
                                       m1, t1, t1, a1, ld1, b1, lh1, hl1, hh1);
    dwt2_fused<<<g2, blk, 0, stream>>>(a1, n2, ld1, b1,
                                       m2, t2_, t2_, a2, ld2, b2, lh2, hl2, hh2);
    dwt2_fused<<<g3, blk, 0, stream>>>(a2, n3, ld2, b2,
                                       m3, t3, t3, out, m3, m3 * m3, lh3, hl3, hh3);
}